// Round 6
// baseline (31857.785 us; speedup 1.0000x reference)
//
#include <hip/hip_runtime.h>

// ---------------------------------------------------------------------------
// GRU forecaster: B=32, T=2048, I=256, H=512, L=2, O=64   (f16 datapath)
// Scan: 2 clusters (16 batches each) x 8 WGs x 256 thr (grid=16; cooperative
// launch with plain-launch fallback -- 16 blocks are de-facto co-resident).
// Recurrent matvec as MFMA 16x16x32_f16 with M=batch: per wave 3 gate N-tiles
// x 16 K-tiles = 48 MFMA; 48 B-fragments loaded once as MFMA operands.
// h exchange: u64 {epoch32|f16pair} agent-scope tokens; LDS h staged so the
// A-fragment ds_read_b128 is contiguous and conflict-free.
// ---------------------------------------------------------------------------

typedef unsigned int  u32;
typedef unsigned short u16;
typedef unsigned long long u64;
typedef float v4f __attribute__((ext_vector_type(4)));
typedef _Float16 v8h __attribute__((ext_vector_type(8)));

__device__ __forceinline__ u16 f2h(float f) {
    _Float16 h = (_Float16)f;
    return *(u16*)&h;
}
__device__ __forceinline__ float h2f(u16 b) {
    _Float16 h = *(_Float16*)&b;
    return (float)h;
}

// --------------------------- prep kernels ----------------------------------

// src fp32 [R][C] -> dst f16 [C][R]  (32x32 tiles)
__global__ __launch_bounds__(256) void transpose_cast(const float* __restrict__ src,
                                                      u16* __restrict__ dst,
                                                      int R, int C) {
    __shared__ u16 tile[32][33];
    int c0 = blockIdx.x * 32, r0 = blockIdx.y * 32;
    int t = threadIdx.x;
    {
        int rl = t >> 3, cl4 = (t & 7) * 4;
        float4 v = *(const float4*)&src[(size_t)(r0 + rl) * C + c0 + cl4];
        tile[rl][cl4 + 0] = f2h(v.x);
        tile[rl][cl4 + 1] = f2h(v.y);
        tile[rl][cl4 + 2] = f2h(v.z);
        tile[rl][cl4 + 3] = f2h(v.w);
    }
    __syncthreads();
    {
        int cl = t >> 3, rl4 = (t & 7) * 4;
        uint2 o;
        o.x = (u32)tile[rl4 + 0][cl] | ((u32)tile[rl4 + 1][cl] << 16);
        o.y = (u32)tile[rl4 + 2][cl] | ((u32)tile[rl4 + 3][cl] << 16);
        *(uint2*)&dst[(size_t)(c0 + cl) * R + r0 + rl4] = o;
    }
}

// Wh fp32 [512][1536] -> f16 B-fragments: uint4 index
//   ((mw*3 + g)*16 + kt)*64 + lane   (mw = member*4 + w, 0..31)
// lane's uint4 = W[k = kt*32 + (lane>>4)*8 + 0..7][g*512 + member*64 + w*16 + (lane&15)]
__global__ __launch_bounds__(256) void pack_wh(const float* __restrict__ Wh,
                                               uint4* __restrict__ dst) {
    int id = blockIdx.x * 256 + threadIdx.x;   // < 98304
    int lane = id & 63;
    int kt = (id >> 6) & 15;
    int top = id >> 10;                        // mw*3 + g
    int g = top % 3, mw = top / 3;
    int col = g * 512 + (mw >> 2) * 64 + (mw & 3) * 16 + (lane & 15);
    int kb = kt * 32 + (lane >> 4) * 8;
    u32 d[4];
#pragma unroll
    for (int p = 0; p < 4; ++p) {
        u16 a = f2h(Wh[(size_t)(kb + 2 * p) * 1536 + col]);
        u16 b = f2h(Wh[(size_t)(kb + 2 * p + 1) * 1536 + col]);
        d[p] = (u32)a | ((u32)b << 16);
    }
    uint4 o; o.x = d[0]; o.y = d[1]; o.z = d[2]; o.w = d[3];
    dst[id] = o;
}

// ---------------- GEMM: xi_chunk = A_rows @ Bt^T + bias -> f16 --------------
template <int K, bool AF32>
__global__ __launch_bounds__(256) void gemm_xi(const void* __restrict__ Ap,
                                               const u16* __restrict__ Bt,
                                               const float* __restrict__ bias,
                                               u16* __restrict__ C,
                                               int t0, int lgTc) {
    __shared__ u16 As[64 * 40];
    __shared__ u16 Bs[64 * 40];
    const int tid = threadIdx.x;
    const int n0 = blockIdx.x * 64;
    const int m0 = blockIdx.y * 64;
    const int row = tid >> 2, koff = (tid & 3) * 8;
    const int lane = tid & 63, w = tid >> 6;
    const int m = m0 + row;
    const int b = m >> lgTc;
    const int tl = m & ((1 << lgTc) - 1);
    const size_t srow = ((size_t)b << 11) + (size_t)(t0 + tl);
    v4f acc[4];
#pragma unroll
    for (int i = 0; i < 4; ++i) acc[i] = (v4f){0.f, 0.f, 0.f, 0.f};

    for (int k0 = 0; k0 < K; k0 += 32) {
        if (AF32) {
            const float* A = (const float*)Ap;
            float4 v0 = *(const float4*)&A[srow * K + k0 + koff];
            float4 v1 = *(const float4*)&A[srow * K + k0 + koff + 4];
            uint4 o;
            o.x = (u32)f2h(v0.x) | ((u32)f2h(v0.y) << 16);
            o.y = (u32)f2h(v0.z) | ((u32)f2h(v0.w) << 16);
            o.z = (u32)f2h(v1.x) | ((u32)f2h(v1.y) << 16);
            o.w = (u32)f2h(v1.z) | ((u32)f2h(v1.w) << 16);
            *(uint4*)&As[row * 40 + koff] = o;
        } else {
            const u16* A = (const u16*)Ap;
            *(uint4*)&As[row * 40 + koff] =
                *(const uint4*)&A[srow * K + k0 + koff];
        }
        *(uint4*)&Bs[row * 40 + koff] =
            *(const uint4*)&Bt[(size_t)(n0 + row) * K + k0 + koff];
        __syncthreads();
        v8h a = *(const v8h*)&As[(w * 16 + (lane & 15)) * 40 + (lane >> 4) * 8];
#pragma unroll
        for (int nt = 0; nt < 4; ++nt) {
            v8h bm = *(const v8h*)&Bs[(nt * 16 + (lane & 15)) * 40 + (lane >> 4) * 8];
            acc[nt] = __builtin_amdgcn_mfma_f32_16x16x32_f16(a, bm, acc[nt], 0, 0, 0);
        }
        __syncthreads();
    }
#pragma unroll
    for (int nt = 0; nt < 4; ++nt) {
        int col = n0 + nt * 16 + (lane & 15);
        float bv = bias[col];
#pragma unroll
        for (int rI = 0; rI < 4; ++rI) {
            int rowm = m0 + w * 16 + (lane >> 4) * 4 + rI;
            C[(size_t)rowm * 1536 + col] = f2h(acc[nt][rI] + bv);
        }
    }
}

// --------------------------- GRU scan --------------------------------------
// grid = 16 x 256. cluster = blockIdx & 1 (batches [16c,16c+16)), member =
// blockIdx >> 1. Wave w owns j = member*64 + w*16 + (lane&15); lane computes
// cells (b = (lane>>4)*4 + rI, j) for rI 0..3. Tokens: Tok[cluster][parity]
// [b(16)][jp(256)] u64 = {epoch32 | f16pair}.
__global__ __launch_bounds__(256, 1) void gru_scan(const u16* __restrict__ xi,
                                                   const uint4* __restrict__ Whp,
                                                   const float* __restrict__ bhn,
                                                   u64* __restrict__ Tok,
                                                   u32* __restrict__ hseq,
                                                   float* __restrict__ h1last,
                                                   float* __restrict__ hstate,
                                                   int t0, int Tc, int layer0) {
    __shared__ uint4 LH[2][1024];   // [parity][kt*64 + frag-lane] 16B chunks

    const int tid = threadIdx.x;
    const int cluster = blockIdx.x & 1;
    const int member = blockIdx.x >> 1;
    const int w = tid >> 6, lane = tid & 63;
    const int quad = lane >> 4;
    const int j = member * 64 + w * 16 + (lane & 15);

    // B-fragments: loaded once, MFMA operands
    v8h Bf[48];
    {
        const uint4* src = Whp + (size_t)(member * 4 + w) * 3072 + lane;
#pragma unroll
        for (int c = 0; c < 48; ++c) {
            uint4 v = src[c * 64];
            Bf[c] = *(v8h*)&v;
        }
    }

    u64* tokBase = Tok + (size_t)cluster * 8192;   // 2 parity x 16 b x 256 jp
    const int b_c = tid >> 4, i_c = tid & 15;      // consumer role

    // init LDS parity (t0&1) with h_{t0-1}
    {
        u32* lw = (u32*)&LH[t0 & 1][0];
#pragma unroll
        for (int q = 0; q < 16; ++q) {
            u32 v = 0;
            if (t0 > 0)
                v = (u32)tokBase[(size_t)((t0 - 1) & 1) * 4096 + b_c * 256 + i_c + 16 * q];
            lw[q * 256 + (b_c + 16 * (i_c >> 2)) * 4 + (i_c & 3)] = v;
        }
    }

    const float bhnv = bhn[j];
    float hp[4];
    u16 rxv[4], rzv[4], rnv[4];
#pragma unroll
    for (int rI = 0; rI < 4; ++rI) {
        int bgl = cluster * 16 + quad * 4 + rI;
        hp[rI] = (t0 > 0) ? hstate[bgl * 512 + j] : 0.f;
        const u16* p = xi + (size_t)bgl * Tc * 1536 + j;
        rxv[rI] = p[0]; rzv[rI] = p[512]; rnv[rI] = p[1024];
    }
    __syncthreads();

    for (int t = t0; t < t0 + Tc; ++t) {
        // ---- MFMA: 3 gates x 16 K-tiles, M=16 batches, N=16 j's
        v4f aR = (v4f){0.f, 0.f, 0.f, 0.f};
        v4f aZ = aR, aN = aR;
        const uint4* lhp = &LH[t & 1][0];
#pragma unroll
        for (int kt = 0; kt < 16; ++kt) {
            uint4 av = lhp[kt * 64 + lane];
            v8h a = *(v8h*)&av;
            aR = __builtin_amdgcn_mfma_f32_16x16x32_f16(a, Bf[kt],      aR, 0, 0, 0);
            aZ = __builtin_amdgcn_mfma_f32_16x16x32_f16(a, Bf[16 + kt], aZ, 0, 0, 0);
            aN = __builtin_amdgcn_mfma_f32_16x16x32_f16(a, Bf[32 + kt], aN, 0, 0, 0);
        }
        // ---- finalize 4 cells/lane (b = quad*4 + rI), publish tokens
        u64* slot = tokBase + (size_t)(t & 1) * 4096;
        u32 hv[4];
#pragma unroll
        for (int rI = 0; rI < 4; ++rI) {
            float r = 1.f / (1.f + __expf(-(h2f(rxv[rI]) + aR[rI])));
            float z = 1.f / (1.f + __expf(-(h2f(rzv[rI]) + aZ[rI])));
            float nx = h2f(rnv[rI]) + r * (aN[rI] + bhnv);
            float n = 1.f - 2.f / (__expf(2.f * nx) + 1.f);   // tanh
            float hn = (1.f - z) * n + z * hp[rI];
            hp[rI] = hn;
            hv[rI] = (u32)f2h(hn);
        }
        const u64 ep = (u64)(u32)(t + 1) << 32;
        const int jp = j >> 1;
#pragma unroll
        for (int rI = 0; rI < 4; ++rI) {
            u32 nb = (u32)__shfl_down((int)hv[rI], 1);
            if ((lane & 1) == 0) {
                u32 pair = hv[rI] | (nb << 16);
                int b = quad * 4 + rI;
                __hip_atomic_store(&slot[b * 256 + jp], (u64)pair | ep,
                                   __ATOMIC_RELAXED, __HIP_MEMORY_SCOPE_AGENT);
                if (layer0)
                    hseq[((size_t)(cluster * 16 + b) * 2048 + t) * 256 + jp] = pair;
            }
        }
        if (!layer0 && t == 2047) {
#pragma unroll
            for (int rI = 0; rI < 4; ++rI)
                h1last[(cluster * 16 + quad * 4 + rI) * 512 + j] = hp[rI];
        }
        // prefetch xi for t+1 (independent of h; hidden by poll)
        if (t + 1 < t0 + Tc) {
#pragma unroll
            for (int rI = 0; rI < 4; ++rI) {
                int bgl = cluster * 16 + quad * 4 + rI;
                const u16* p = xi + ((size_t)bgl * Tc + (t + 1 - t0)) * 1536 + j;
                rxv[rI] = p[0]; rzv[rI] = p[512]; rnv[rI] = p[1024];
            }
        }
        // ---- poll 16 tokens, deposit into next parity LDS
        {
            const u32 target = (u32)(t + 1);
            u32* lw = (u32*)&LH[(t + 1) & 1][0];
#pragma unroll
            for (int q = 0; q < 16; ++q) {
                u64* myq = &slot[b_c * 256 + i_c + 16 * q];
                u64 qv = 0;
                for (int it = 0; it < 8000000; ++it) {
                    qv = __hip_atomic_load(myq, __ATOMIC_RELAXED, __HIP_MEMORY_SCOPE_AGENT);
                    if ((u32)(qv >> 32) == target) break;
                    __builtin_amdgcn_s_sleep(1);
                }
                lw[q * 256 + (b_c + 16 * (i_c >> 2)) * 4 + (i_c & 3)] = (u32)qv;
            }
        }
        __syncthreads();
    }
#pragma unroll
    for (int rI = 0; rI < 4; ++rI)
        hstate[(cluster * 16 + quad * 4 + rI) * 512 + j] = hp[rI];
}

// --------------------------- final FC --------------------------------------
__global__ __launch_bounds__(64) void final_fc(const float* __restrict__ h1,
                                               const float* __restrict__ Wfc,
                                               const float* __restrict__ bfc,
                                               float* __restrict__ out) {
    int b = blockIdx.x, o = threadIdx.x;
    float acc = bfc[o];
    for (int k = 0; k < 512; ++k) acc += h1[b * 512 + k] * Wfc[k * 64 + o];
    out[b * 64 + o] = acc;
}

// --------------------------- launch ----------------------------------------

static void launch_scan(const u16* xi, const uint4* wh, const float* bh,
                        u64* tk, u32* hs, float* h1, float* st,
                        int t0, int Tc, int l0, hipStream_t stream) {
    const u16* xi_p = xi; const uint4* wh_p = wh; const float* bh_p = bh;
    u64* tk_p = tk; u32* hs_p = hs; float* h1_p = h1; float* st_p = st;
    int t0v = t0, Tcv = Tc, l0v = l0;
    void* args[] = {&xi_p, &wh_p, &bh_p, &tk_p, &hs_p, &h1_p, &st_p,
                    &t0v, &Tcv, &l0v};
    hipError_t e = hipLaunchCooperativeKernel(gru_scan, dim3(16), dim3(256),
                                              args, 0, stream);
    if (e != hipSuccess) {
        // 16 blocks on 256 CUs are de-facto co-resident; bounded spins make
        // any residency failure a visible wrong answer, not a hang.
        gru_scan<<<dim3(16), dim3(256), 0, stream>>>(xi, wh, bh, tk, hs, h1,
                                                     st, t0, Tc, l0);
    }
}

extern "C" void kernel_launch(void* const* d_in, const int* in_sizes, int n_in,
                              void* d_out, int out_size, void* d_ws, size_t ws_size,
                              hipStream_t stream) {
    const float* x    = (const float*)d_in[0];
    const float* Wi0  = (const float*)d_in[1];
    const float* bi0  = (const float*)d_in[2];
    const float* Wh0  = (const float*)d_in[3];
    const float* bhn0 = (const float*)d_in[4];
    const float* Wi1  = (const float*)d_in[5];
    const float* bi1  = (const float*)d_in[6];
    const float* Wh1  = (const float*)d_in[7];
    const float* bhn1 = (const float*)d_in[8];
    const float* Wfc  = (const float*)d_in[9];
    const float* bfc  = (const float*)d_in[10];
    float* out = (float*)d_out;
    (void)in_sizes; (void)n_in; (void)out_size;

    char* ws = (char*)d_ws;
    size_t off = 0;
    auto take = [&](size_t bytes) -> char* {
        char* p = ws + off;
        off = (off + bytes + 255) & ~(size_t)255;
        return p;
    };
    u16*  Wi0t  = (u16*)take(1536 * 256 * 2);
    u16*  Wi1t  = (u16*)take(1536 * 512 * 2);
    uint4* Wh0p = (uint4*)take(98304 * 16);
    uint4* Wh1p = (uint4*)take(98304 * 16);
    u64*  Tok0  = (u64*)take(2 * 8192 * 8);
    u64*  Tok1  = (u64*)take(2 * 8192 * 8);
    float* hstate = (float*)take(32 * 512 * 4);
    float* h1last = (float*)take(32 * 512 * 4);
    u16*  h0seq = (u16*)take((size_t)32 * 2048 * 512 * 2);
    size_t fixed_end = off;

    int Tc = 2048;
    if (ws_size > 0) {
        while (Tc > 128 &&
               fixed_end + (size_t)32 * Tc * 1536 * 2 > ws_size) Tc >>= 1;
    }
    int lgTc = 31 - __builtin_clz((u32)Tc);
    u16* xibuf = (u16*)take((size_t)32 * Tc * 1536 * 2);
    int nChunk = 2048 / Tc;

    // prep
    transpose_cast<<<dim3(48, 8), 256, 0, stream>>>(Wi0, Wi0t, 256, 1536);
    transpose_cast<<<dim3(48, 16), 256, 0, stream>>>(Wi1, Wi1t, 512, 1536);
    pack_wh<<<384, 256, 0, stream>>>(Wh0, Wh0p);
    pack_wh<<<384, 256, 0, stream>>>(Wh1, Wh1p);

    // layer 0
    for (int c = 0; c < nChunk; ++c) {
        int t0 = c * Tc;
        gemm_xi<256, true><<<dim3(24, Tc / 2), 256, 0, stream>>>(
            (const void*)x, Wi0t, bi0, xibuf, t0, lgTc);
        launch_scan(xibuf, Wh0p, bhn0, Tok0, (u32*)h0seq, nullptr, hstate,
                    t0, Tc, 1, stream);
    }
    // layer 1
    for (int c = 0; c < nChunk; ++c) {
        int t0 = c * Tc;
        gemm_xi<512, false><<<dim3(24, Tc / 2), 256, 0, stream>>>(
            (const void*)h0seq, Wi1t, bi1, xibuf, t0, lgTc);
        launch_scan(xibuf, Wh1p, bhn1, Tok1, nullptr, h1last, hstate,
                    t0, Tc, 0, stream);
    }
    final_fc<<<32, 64, 0, stream>>>(h1last, Wfc, bfc, out);
}

// Round 7
// 10655.444 us; speedup vs baseline: 2.9898x; 2.9898x over previous
//
#include <hip/hip_runtime.h>

// ---------------------------------------------------------------------------
// GRU forecaster: B=32, T=2048, I=256, H=512, L=2, O=64   (f16 datapath)
// Scan: 8 clusters (4 batches each) x 8 members x 256 thr, grid=64, plain
// launch (co-resident on 256 CUs). Recurrent matvec via MFMA 16x16x32_f16
// (M rows 0..3 = batches, rows 4..15 zero); 48 B-fragments (weights) loaded
// once as MFMA operands (register-resident). h exchange: u64 {epoch|pair}
// agent-scope tokens, 4/thread polled IN PARALLEL (r6's 16 serial polls were
// the 7.7us/step bottleneck). One barrier/step, parity-double-buffered LDS.
// ---------------------------------------------------------------------------

typedef unsigned int  u32;
typedef unsigned short u16;
typedef unsigned long long u64;
typedef float v4f __attribute__((ext_vector_type(4)));
typedef _Float16 v8h __attribute__((ext_vector_type(8)));

__device__ __forceinline__ u16 f2h(float f) {
    _Float16 h = (_Float16)f;
    return *(u16*)&h;
}
__device__ __forceinline__ float h2f(u16 b) {
    _Float16 h = *(_Float16*)&b;
    return (float)h;
}

// --------------------------- prep kernels ----------------------------------

// src fp32 [R][C] -> dst f16 [C][R]  (32x32 tiles)
__global__ __launch_bounds__(256) void transpose_cast(const float* __restrict__ src,
                                                      u16* __restrict__ dst,
                                                      int R, int C) {
    __shared__ u16 tile[32][33];
    int c0 = blockIdx.x * 32, r0 = blockIdx.y * 32;
    int t = threadIdx.x;
    {
        int rl = t >> 3, cl4 = (t & 7) * 4;
        float4 v = *(const float4*)&src[(size_t)(r0 + rl) * C + c0 + cl4];
        tile[rl][cl4 + 0] = f2h(v.x);
        tile[rl][cl4 + 1] = f2h(v.y);
        tile[rl][cl4 + 2] = f2h(v.z);
        tile[rl][cl4 + 3] = f2h(v.w);
    }
    __syncthreads();
    {
        int cl = t >> 3, rl4 = (t & 7) * 4;
        uint2 o;
        o.x = (u32)tile[rl4 + 0][cl] | ((u32)tile[rl4 + 1][cl] << 16);
        o.y = (u32)tile[rl4 + 2][cl] | ((u32)tile[rl4 + 3][cl] << 16);
        *(uint2*)&dst[(size_t)(c0 + cl) * R + r0 + rl4] = o;
    }
}

// Wh fp32 [512][1536] -> f16 B-fragments: uint4 index
//   ((mw*3 + g)*16 + kt)*64 + lane   (mw = member*4 + w, 0..31)
// lane's uint4 = W[k = kt*32 + (lane>>4)*8 + 0..7][g*512 + member*64 + w*16 + (lane&15)]
__global__ __launch_bounds__(256) void pack_wh(const float* __restrict__ Wh,
                                               uint4* __restrict__ dst) {
    int id = blockIdx.x * 256 + threadIdx.x;   // < 98304
    int lane = id & 63;
    int kt = (id >> 6) & 15;
    int top = id >> 10;                        // mw*3 + g
    int g = top % 3, mw = top / 3;
    int col = g * 512 + (mw >> 2) * 64 + (mw & 3) * 16 + (lane & 15);
    int kb = kt * 32 + (lane >> 4) * 8;
    u32 d[4];
#pragma unroll
    for (int p = 0; p < 4; ++p) {
        u16 a = f2h(Wh[(size_t)(kb + 2 * p) * 1536 + col]);
        u16 b = f2h(Wh[(size_t)(kb + 2 * p + 1) * 1536 + col]);
        d[p] = (u32)a | ((u32)b << 16);
    }
    uint4 o; o.x = d[0]; o.y = d[1]; o.z = d[2]; o.w = d[3];
    dst[id] = o;
}

// ---------------- GEMM: xi_chunk = A_rows @ Bt^T + bias -> f16 --------------
template <int K, bool AF32>
__global__ __launch_bounds__(256) void gemm_xi(const void* __restrict__ Ap,
                                               const u16* __restrict__ Bt,
                                               const float* __restrict__ bias,
                                               u16* __restrict__ C,
                                               int t0, int lgTc) {
    __shared__ u16 As[64 * 40];
    __shared__ u16 Bs[64 * 40];
    const int tid = threadIdx.x;
    const int n0 = blockIdx.x * 64;
    const int m0 = blockIdx.y * 64;
    const int row = tid >> 2, koff = (tid & 3) * 8;
    const int lane = tid & 63, w = tid >> 6;
    const int m = m0 + row;
    const int b = m >> lgTc;
    const int tl = m & ((1 << lgTc) - 1);
    const size_t srow = ((size_t)b << 11) + (size_t)(t0 + tl);
    v4f acc[4];
#pragma unroll
    for (int i = 0; i < 4; ++i) acc[i] = (v4f){0.f, 0.f, 0.f, 0.f};

    for (int k0 = 0; k0 < K; k0 += 32) {
        if (AF32) {
            const float* A = (const float*)Ap;
            float4 v0 = *(const float4*)&A[srow * K + k0 + koff];
            float4 v1 = *(const float4*)&A[srow * K + k0 + koff + 4];
            uint4 o;
            o.x = (u32)f2h(v0.x) | ((u32)f2h(v0.y) << 16);
            o.y = (u32)f2h(v0.z) | ((u32)f2h(v0.w) << 16);
            o.z = (u32)f2h(v1.x) | ((u32)f2h(v1.y) << 16);
            o.w = (u32)f2h(v1.z) | ((u32)f2h(v1.w) << 16);
            *(uint4*)&As[row * 40 + koff] = o;
        } else {
            const u16* A = (const u16*)Ap;
            *(uint4*)&As[row * 40 + koff] =
                *(const uint4*)&A[srow * K + k0 + koff];
        }
        *(uint4*)&Bs[row * 40 + koff] =
            *(const uint4*)&Bt[(size_t)(n0 + row) * K + k0 + koff];
        __syncthreads();
        v8h a = *(const v8h*)&As[(w * 16 + (lane & 15)) * 40 + (lane >> 4) * 8];
#pragma unroll
        for (int nt = 0; nt < 4; ++nt) {
            v8h bm = *(const v8h*)&Bs[(nt * 16 + (lane & 15)) * 40 + (lane >> 4) * 8];
            acc[nt] = __builtin_amdgcn_mfma_f32_16x16x32_f16(a, bm, acc[nt], 0, 0, 0);
        }
        __syncthreads();
    }
#pragma unroll
    for (int nt = 0; nt < 4; ++nt) {
        int col = n0 + nt * 16 + (lane & 15);
        float bv = bias[col];
#pragma unroll
        for (int rI = 0; rI < 4; ++rI) {
            int rowm = m0 + w * 16 + (lane >> 4) * 4 + rI;
            C[(size_t)rowm * 1536 + col] = f2h(acc[nt][rI] + bv);
        }
    }
}

// --------------------------- GRU scan --------------------------------------
// grid = 64 x 256. cluster = blockIdx & 7 (batches [4c,4c+4)), member =
// blockIdx >> 3 (j in [64m, 64m+64)). Wave w owns j = member*64 + w*16 +
// (lane&15); quad-0 lanes finalize 4 cells (b = 0..3). Tokens:
// Tok[cluster][parity][b(4)][jp(256)] u64 = {epoch32 | f16pair}.
__global__ __launch_bounds__(256, 1) void gru_scan(const u16* __restrict__ xi,
                                                   const uint4* __restrict__ Whp,
                                                   const float* __restrict__ bhn,
                                                   u64* __restrict__ Tok,
                                                   u32* __restrict__ hseq,
                                                   float* __restrict__ h1last,
                                                   float* __restrict__ hstate,
                                                   int t0, int Tc, int layer0) {
    __shared__ uint4 LH[2][1024];   // [parity][kt*64 + frag-lane]

    const int tid = threadIdx.x;
    const int cluster = blockIdx.x & 7;
    const int member = blockIdx.x >> 3;
    const int w = tid >> 6, lane = tid & 63;
    const int quad = lane >> 4;
    const int j = member * 64 + w * 16 + (lane & 15);

    // B-fragments (weights): loaded once, MFMA operands
    v8h Bf[48];
    {
        const uint4* src = Whp + (size_t)(member * 4 + w) * 3072 + lane;
#pragma unroll
        for (int c = 0; c < 48; ++c) {
            uint4 v = src[c * 64];
            Bf[c] = *(v8h*)&v;
        }
    }

    u64* tokBase = Tok + (size_t)cluster * 2048;   // 2 parity x 4 b x 256 jp
    // consumer: 4 tokens (b_t, jpb + 64q), q = 0..3
    const int b_t = tid & 3, jpb = tid >> 2;
    // deposit coords (q-invariant parts): k = 2*jpb + 128q
    const int kt0 = jpb >> 4;                  // + 4q per q
    const int koff = (2 * jpb) & 31;
    const int qc = koff >> 3, sOff = (koff >> 1) & 3;
    const int depBase = (qc * 16 + b_t) * 4 + sOff;   // + (kt0+4q)*256

    // zero both LDS parities (rows m>=4 stay zero forever)
    {
        uint4 z = (uint4){0u, 0u, 0u, 0u};
#pragma unroll
        for (int i = 0; i < 8; ++i) ((uint4*)LH)[tid + 256 * i] = z;
    }
    __syncthreads();

    // init parity (t0&1) with h_{t0-1}
    if (t0 > 0) {
        u32* lw = (u32*)&LH[t0 & 1][0];
#pragma unroll
        for (int q = 0; q < 4; ++q) {
            u64 v = tokBase[(size_t)((t0 - 1) & 1) * 1024 + b_t * 256 + jpb + 64 * q];
            lw[(kt0 + 4 * q) * 256 + depBase] = (u32)v;
        }
    }

    float bhnv = 0.f;
    float hp[4] = {0.f, 0.f, 0.f, 0.f};
    u16 rxv[4], rzv[4], rnv[4];
    if (quad == 0) {
        bhnv = bhn[j];
#pragma unroll
        for (int rI = 0; rI < 4; ++rI) {
            int bg = cluster * 4 + rI;
            if (t0 > 0) hp[rI] = hstate[bg * 512 + j];
            const u16* p = xi + (size_t)bg * Tc * 1536 + j;
            rxv[rI] = p[0]; rzv[rI] = p[512]; rnv[rI] = p[1024];
        }
    }
    __syncthreads();

    for (int t = t0; t < t0 + Tc; ++t) {
        // ---- MFMA: 3 gates x 16 K-tiles (M rows 0..3 = batches)
        v4f aR = (v4f){0.f, 0.f, 0.f, 0.f};
        v4f aZ = aR, aN = aR;
        const uint4* lhp = &LH[t & 1][0];
#pragma unroll
        for (int kt = 0; kt < 16; ++kt) {
            uint4 av = lhp[kt * 64 + lane];
            v8h a = *(v8h*)&av;
            aR = __builtin_amdgcn_mfma_f32_16x16x32_f16(a, Bf[kt],      aR, 0, 0, 0);
            aZ = __builtin_amdgcn_mfma_f32_16x16x32_f16(a, Bf[16 + kt], aZ, 0, 0, 0);
            aN = __builtin_amdgcn_mfma_f32_16x16x32_f16(a, Bf[32 + kt], aN, 0, 0, 0);
        }
        u64* slot = tokBase + (size_t)(t & 1) * 1024;
        if (quad == 0) {
            // finalize cells (b = rI, j); D row rI lives in lane quad 0, reg rI
            u32 hv[4];
#pragma unroll
            for (int rI = 0; rI < 4; ++rI) {
                float r = 1.f / (1.f + __expf(-(h2f(rxv[rI]) + aR[rI])));
                float z = 1.f / (1.f + __expf(-(h2f(rzv[rI]) + aZ[rI])));
                float nx = h2f(rnv[rI]) + r * (aN[rI] + bhnv);
                float n = 1.f - 2.f / (__expf(2.f * nx) + 1.f);   // tanh
                float hn = (1.f - z) * n + z * hp[rI];
                hp[rI] = hn;
                hv[rI] = (u32)f2h(hn);
            }
            const u64 ep = (u64)(u32)(t + 1) << 32;
            const int jp = j >> 1;
#pragma unroll
            for (int rI = 0; rI < 4; ++rI) {
                u32 nb = (u32)__shfl_down((int)hv[rI], 1);
                if ((lane & 1) == 0) {
                    u32 pair = hv[rI] | (nb << 16);
                    __hip_atomic_store(&slot[rI * 256 + jp], (u64)pair | ep,
                                       __ATOMIC_RELAXED, __HIP_MEMORY_SCOPE_AGENT);
                    if (layer0)
                        hseq[((size_t)(cluster * 4 + rI) * 2048 + t) * 256 + jp] = pair;
                }
            }
            if (!layer0 && t == 2047) {
#pragma unroll
                for (int rI = 0; rI < 4; ++rI)
                    h1last[(cluster * 4 + rI) * 512 + j] = hp[rI];
            }
            if (t + 1 < t0 + Tc) {   // prefetch xi for t+1
#pragma unroll
                for (int rI = 0; rI < 4; ++rI) {
                    const u16* p = xi + ((size_t)(cluster * 4 + rI) * Tc + (t + 1 - t0)) * 1536 + j;
                    rxv[rI] = p[0]; rzv[rI] = p[512]; rnv[rI] = p[1024];
                }
            }
        }
        // ---- poll 4 tokens IN PARALLEL, deposit into next parity
        {
            const u32 target = (u32)(t + 1);
            u64* p0 = &slot[b_t * 256 + jpb];
            u64 v0, v1, v2, v3;
            int it = 0;
            for (;;) {
                v0 = __hip_atomic_load(p0,       __ATOMIC_RELAXED, __HIP_MEMORY_SCOPE_AGENT);
                v1 = __hip_atomic_load(p0 + 64,  __ATOMIC_RELAXED, __HIP_MEMORY_SCOPE_AGENT);
                v2 = __hip_atomic_load(p0 + 128, __ATOMIC_RELAXED, __HIP_MEMORY_SCOPE_AGENT);
                v3 = __hip_atomic_load(p0 + 192, __ATOMIC_RELAXED, __HIP_MEMORY_SCOPE_AGENT);
                if ((u32)(v0 >> 32) == target && (u32)(v1 >> 32) == target &&
                    (u32)(v2 >> 32) == target && (u32)(v3 >> 32) == target) break;
                if (++it > 50000) break;   // pathology -> visible wrong answer
            }
            u32* lw = (u32*)&LH[(t + 1) & 1][0];
            lw[(kt0 +  0) * 256 + depBase] = (u32)v0;
            lw[(kt0 +  4) * 256 + depBase] = (u32)v1;
            lw[(kt0 +  8) * 256 + depBase] = (u32)v2;
            lw[(kt0 + 12) * 256 + depBase] = (u32)v3;
        }
        __syncthreads();
    }
    if (quad == 0) {
#pragma unroll
        for (int rI = 0; rI < 4; ++rI)
            hstate[(cluster * 4 + rI) * 512 + j] = hp[rI];
    }
}

// --------------------------- final FC --------------------------------------
__global__ __launch_bounds__(64) void final_fc(const float* __restrict__ h1,
                                               const float* __restrict__ Wfc,
                                               const float* __restrict__ bfc,
                                               float* __restrict__ out) {
    int b = blockIdx.x, o = threadIdx.x;
    float acc = bfc[o];
    for (int k = 0; k < 512; ++k) acc += h1[b * 512 + k] * Wfc[k * 64 + o];
    out[b * 64 + o] = acc;
}

// --------------------------- launch ----------------------------------------

extern "C" void kernel_launch(void* const* d_in, const int* in_sizes, int n_in,
                              void* d_out, int out_size, void* d_ws, size_t ws_size,
                              hipStream_t stream) {
    const float* x    = (const float*)d_in[0];
    const float* Wi0  = (const float*)d_in[1];
    const float* bi0  = (const float*)d_in[2];
    const float* Wh0  = (const float*)d_in[3];
    const float* bhn0 = (const float*)d_in[4];
    const float* Wi1  = (const float*)d_in[5];
    const float* bi1  = (const float*)d_in[6];
    const float* Wh1  = (const float*)d_in[7];
    const float* bhn1 = (const float*)d_in[8];
    const float* Wfc  = (const float*)d_in[9];
    const float* bfc  = (const float*)d_in[10];
    float* out = (float*)d_out;
    (void)in_sizes; (void)n_in; (void)out_size;

    char* ws = (char*)d_ws;
    size_t off = 0;
    auto take = [&](size_t bytes) -> char* {
        char* p = ws + off;
        off = (off + bytes + 255) & ~(size_t)255;
        return p;
    };
    u16*  Wi0t  = (u16*)take(1536 * 256 * 2);
    u16*  Wi1t  = (u16*)take(1536 * 512 * 2);
    uint4* Wh0p = (uint4*)take(98304 * 16);
    uint4* Wh1p = (uint4*)take(98304 * 16);
    u64*  Tok0  = (u64*)take(8 * 2048 * 8);      // 8 clusters x 2 parity x 4b x 256jp
    u64*  Tok1  = (u64*)take(8 * 2048 * 8);
    float* hstate = (float*)take(32 * 512 * 4);
    float* h1last = (float*)take(32 * 512 * 4);
    u16*  h0seq = (u16*)take((size_t)32 * 2048 * 512 * 2);
    size_t fixed_end = off;

    int Tc = 2048;
    if (ws_size > 0) {
        while (Tc > 128 &&
               fixed_end + (size_t)32 * Tc * 1536 * 2 > ws_size) Tc >>= 1;
    }
    int lgTc = 31 - __builtin_clz((u32)Tc);
    u16* xibuf = (u16*)take((size_t)32 * Tc * 1536 * 2);
    int nChunk = 2048 / Tc;

    // prep
    transpose_cast<<<dim3(48, 8), 256, 0, stream>>>(Wi0, Wi0t, 256, 1536);
    transpose_cast<<<dim3(48, 16), 256, 0, stream>>>(Wi1, Wi1t, 512, 1536);
    pack_wh<<<384, 256, 0, stream>>>(Wh0, Wh0p);
    pack_wh<<<384, 256, 0, stream>>>(Wh1, Wh1p);

    // layer 0
    for (int c = 0; c < nChunk; ++c) {
        int t0 = c * Tc;
        gemm_xi<256, true><<<dim3(24, Tc / 2), 256, 0, stream>>>(
            (const void*)x, Wi0t, bi0, xibuf, t0, lgTc);
        gru_scan<<<dim3(64), dim3(256), 0, stream>>>(
            xibuf, Wh0p, bhn0, Tok0, (u32*)h0seq, nullptr, hstate, t0, Tc, 1);
    }
    // layer 1
    for (int c = 0; c < nChunk; ++c) {
        int t0 = c * Tc;
        gemm_xi<512, false><<<dim3(24, Tc / 2), 256, 0, stream>>>(
            (const void*)h0seq, Wi1t, bi1, xibuf, t0, lgTc);
        gru_scan<<<dim3(64), dim3(256), 0, stream>>>(
            xibuf, Wh1p, bhn1, Tok1, nullptr, h1last, hstate, t0, Tc, 0);
    }
    final_fc<<<32, 64, 0, stream>>>(h1last, Wfc, bfc, out);
}